// Round 1
// baseline (295.069 us; speedup 1.0000x reference)
//
#include <hip/hip_runtime.h>
#include <cstddef>

#define BB 16
#define SS 4096
#define DD 2048
#define AA 2048

// ---------------- kernel 1: hp[b,a] = hid[b,:]·W[a,:] + bias[a] ----------------
// one wave per a; all 16 b accumulated simultaneously; lanes over d (float4).
__global__ __launch_bounds__(256) void hp_kernel(
    const float* __restrict__ hid, const float* __restrict__ W,
    const float* __restrict__ bias, float* __restrict__ hp) {
  int gw   = (blockIdx.x * 256 + threadIdx.x) >> 6;  // global wave id = a
  int lane = threadIdx.x & 63;
  int a = gw;
  const float4* Wr = reinterpret_cast<const float4*>(W + (size_t)a * DD);
  float acc[BB];
#pragma unroll
  for (int b = 0; b < BB; ++b) acc[b] = 0.f;
#pragma unroll
  for (int k = 0; k < 8; ++k) {
    float4 w4 = Wr[lane + 64 * k];
#pragma unroll
    for (int b = 0; b < BB; ++b) {
      float4 h4 = reinterpret_cast<const float4*>(hid + b * DD)[lane + 64 * k];
      acc[b] += w4.x * h4.x + w4.y * h4.y + w4.z * h4.z + w4.w * h4.w;
    }
  }
  float bi = bias[a];
#pragma unroll
  for (int b = 0; b < BB; ++b) {
    float s = acc[b];
#pragma unroll
    for (int off = 32; off; off >>= 1) s += __shfl_xor(s, off, 64);
    if (lane == 0) hp[b * AA + a] = s + bi;
  }
}

// ---------------- kernel 2: vpart[c][b][d] = sum over a-chunk of hp[b,a]*W[a,d] ----------------
// grid 32 blocks: achunk (16) x dchunk (2). block 256 threads; thread owns float4 at d0.
__global__ __launch_bounds__(256) void vpart_kernel(
    const float* __restrict__ hp, const float* __restrict__ W,
    float* __restrict__ vpart) {
  int t  = threadIdx.x;
  int ac = blockIdx.x & 15;
  int dc = blockIdx.x >> 4;
  int d0 = dc * 1024 + 4 * t;
  float4 acc[BB];
#pragma unroll
  for (int b = 0; b < BB; ++b) acc[b] = make_float4(0.f, 0.f, 0.f, 0.f);
  int abase = ac * 128;
  for (int i = 0; i < 128; ++i) {
    int a = abase + i;
    float4 w4 = *reinterpret_cast<const float4*>(W + (size_t)a * DD + d0);
#pragma unroll
    for (int b = 0; b < BB; ++b) {
      float h = hp[b * AA + a];  // uniform -> scalar load
      acc[b].x += h * w4.x; acc[b].y += h * w4.y;
      acc[b].z += h * w4.z; acc[b].w += h * w4.w;
    }
  }
#pragma unroll
  for (int b = 0; b < BB; ++b)
    *reinterpret_cast<float4*>(vpart + (size_t)(ac * BB + b) * DD + d0) = acc[b];
}

// ---------------- kernel 3: c[b] = sum_a bias[a]*hp[b,a] ----------------
__global__ __launch_bounds__(256) void c_kernel(
    const float* __restrict__ hp, const float* __restrict__ bias,
    float* __restrict__ cvec) {
  int b = blockIdx.x, t = threadIdx.x;
  float s = 0.f;
  for (int i = t; i < AA; i += 256) s += bias[i] * hp[b * AA + i];
#pragma unroll
  for (int off = 32; off; off >>= 1) s += __shfl_xor(s, off, 64);
  __shared__ float red[4];
  if ((t & 63) == 0) red[t >> 6] = s;
  __syncthreads();
  if (t == 0) cvec[b] = red[0] + red[1] + red[2] + red[3];
}

// ---------------- kernel 4: v[b,d] = sum over 16 achunks of vpart ----------------
__global__ __launch_bounds__(256) void reducev_kernel(
    const float* __restrict__ vpart, float* __restrict__ v) {
  int i = blockIdx.x * 256 + threadIdx.x;  // i = b*DD + d, layout folds linearly
  float s = 0.f;
#pragma unroll
  for (int c = 0; c < 16; ++c) s += vpart[(size_t)c * (BB * DD) + i];
  v[i] = s;
}

// ---------------- kernel 5: scores[b,s] = enc[b,s,:]·v[b,:] + c[b] ----------------
// one wave per 8 rows; v cached in registers (8 float4/lane).
__global__ __launch_bounds__(256) void scores_kernel(
    const float* __restrict__ enc, const float* __restrict__ v,
    const float* __restrict__ cvec, float* __restrict__ scores) {
  int gw   = (blockIdx.x * 256 + threadIdx.x) >> 6;  // 8192 waves
  int lane = threadIdx.x & 63;
  int b  = gw >> 9;            // 512 waves per b
  int s0 = (gw & 511) * 8;
  const float4* vp = reinterpret_cast<const float4*>(v + b * DD);
  float4 vf[8];
#pragma unroll
  for (int k = 0; k < 8; ++k) vf[k] = vp[lane + 64 * k];
  float cb = cvec[b];
#pragma unroll
  for (int r = 0; r < 8; ++r) {
    const float4* ep = reinterpret_cast<const float4*>(
        enc + (size_t)(b * SS + s0 + r) * DD);
    float acc = 0.f;
#pragma unroll
    for (int k = 0; k < 8; ++k) {
      float4 e = ep[lane + 64 * k];
      acc += e.x * vf[k].x + e.y * vf[k].y + e.z * vf[k].z + e.w * vf[k].w;
    }
#pragma unroll
    for (int off = 32; off; off >>= 1) acc += __shfl_xor(acc, off, 64);
    if (lane == 0) scores[b * SS + s0 + r] = acc + cb;
  }
}

// ---------------- kernel 6: softmax over s per batch ----------------
__global__ __launch_bounds__(256) void softmax_kernel(
    const float* __restrict__ scores, float* __restrict__ probs) {
  int b = blockIdx.x, t = threadIdx.x;
  const float* sc = scores + b * SS;
  float loc[16];
  float m = -1e30f;
#pragma unroll
  for (int i = 0; i < 16; ++i) {
    loc[i] = sc[t + 256 * i];
    m = fmaxf(m, loc[i]);
  }
#pragma unroll
  for (int off = 32; off; off >>= 1) m = fmaxf(m, __shfl_xor(m, off, 64));
  __shared__ float redm[4];
  if ((t & 63) == 0) redm[t >> 6] = m;
  __syncthreads();
  m = fmaxf(fmaxf(redm[0], redm[1]), fmaxf(redm[2], redm[3]));
  float l = 0.f;
#pragma unroll
  for (int i = 0; i < 16; ++i) {
    loc[i] = __expf(loc[i] - m);
    l += loc[i];
  }
#pragma unroll
  for (int off = 32; off; off >>= 1) l += __shfl_xor(l, off, 64);
  __shared__ float redl[4];
  if ((t & 63) == 0) redl[t >> 6] = l;
  __syncthreads();
  l = redl[0] + redl[1] + redl[2] + redl[3];
  float inv = 1.f / l;
#pragma unroll
  for (int i = 0; i < 16; ++i) probs[b * SS + t + 256 * i] = loc[i] * inv;
}

// ---------------- kernel 7: ctxpart[b][ch][d] = sum over 128 rows of probs*enc ----------------
__global__ __launch_bounds__(256) void ctxpart_kernel(
    const float* __restrict__ enc, const float* __restrict__ probs,
    float* __restrict__ part) {
  int t  = threadIdx.x;
  int b  = blockIdx.x >> 5;   // 32 chunks per b
  int ch = blockIdx.x & 31;
  int sbase = ch * 128;
  float4 a0 = make_float4(0.f, 0.f, 0.f, 0.f);
  float4 a1 = make_float4(0.f, 0.f, 0.f, 0.f);
  const float* pb = probs + b * SS + sbase;
  for (int i = 0; i < 128; ++i) {
    float p = pb[i];  // uniform -> scalar load
    const float4* ep = reinterpret_cast<const float4*>(
        enc + (size_t)(b * SS + sbase + i) * DD);
    float4 e0 = ep[t];
    float4 e1 = ep[256 + t];
    a0.x += p * e0.x; a0.y += p * e0.y; a0.z += p * e0.z; a0.w += p * e0.w;
    a1.x += p * e1.x; a1.y += p * e1.y; a1.z += p * e1.z; a1.w += p * e1.w;
  }
  float4* out = reinterpret_cast<float4*>(part + (size_t)(b * 32 + ch) * DD);
  out[t] = a0;
  out[256 + t] = a1;
}

// ---------------- kernel 8: ctx[b,d] = sum over 32 chunks ----------------
__global__ __launch_bounds__(256) void reducectx_kernel(
    const float* __restrict__ part, float* __restrict__ ctx) {
  int i = blockIdx.x * 256 + threadIdx.x;  // [0, BB*DD)
  int b = i >> 11;
  int d = i & 2047;
  const float* p = part + (size_t)b * 32 * DD + d;
  float s = 0.f;
#pragma unroll
  for (int c = 0; c < 32; ++c) s += p[c * DD];
  ctx[i] = s;
}

extern "C" void kernel_launch(void* const* d_in, const int* in_sizes, int n_in,
                              void* d_out, int out_size, void* d_ws, size_t ws_size,
                              hipStream_t stream) {
  const float* enc  = (const float*)d_in[0];  // [B,S,D]
  const float* hid  = (const float*)d_in[1];  // [B,D]
  const float* W    = (const float*)d_in[2];  // [A,D]
  const float* bias = (const float*)d_in[3];  // [A]

  float* out_scores = (float*)d_out;                 // [B,S]
  float* out_ctx    = (float*)d_out + BB * SS;       // [B,D]

  float* ws    = (float*)d_ws;
  float* hp    = ws;                      // B*A           = 32768
  float* vpart = hp + BB * AA;            // 16*B*D        = 524288
  float* v     = vpart + 16 * BB * DD;    // B*D           = 32768
  float* cvec  = v + BB * DD;             // B             = 16
  float* probs = cvec + BB;               // B*S           = 65536
  float* ctxp  = probs + BB * SS;         // 32*B*D        = 1048576
  // total ~6.8 MB of workspace

  hipLaunchKernelGGL(hp_kernel,      dim3(512), dim3(256), 0, stream, hid, W, bias, hp);
  hipLaunchKernelGGL(vpart_kernel,   dim3(32),  dim3(256), 0, stream, hp, W, vpart);
  hipLaunchKernelGGL(c_kernel,       dim3(16),  dim3(256), 0, stream, hp, bias, cvec);
  hipLaunchKernelGGL(reducev_kernel, dim3(128), dim3(256), 0, stream, vpart, v);
  hipLaunchKernelGGL(scores_kernel,  dim3(2048),dim3(256), 0, stream, enc, v, cvec, out_scores);
  hipLaunchKernelGGL(softmax_kernel, dim3(16),  dim3(256), 0, stream, out_scores, probs);
  hipLaunchKernelGGL(ctxpart_kernel, dim3(512), dim3(256), 0, stream, enc, probs, ctxp);
  hipLaunchKernelGGL(reducectx_kernel, dim3(128), dim3(256), 0, stream, ctxp, out_ctx);
}

// Round 2
// 205.294 us; speedup vs baseline: 1.4373x; 1.4373x over previous
//
#include <hip/hip_runtime.h>
#include <cstddef>

#define BB 16
#define SS 4096
#define DD 2048
#define AA 2048
#define CH 128          // softmax chunks per batch (one wave each, 32 rows)
#define ACH 64          // a-chunks for vpart

// ---------------- kernel 1: hp[b,a] = hid[b,:]·W[a,:] + bias[a] ----------------
__global__ __launch_bounds__(256) void hp_kernel(
    const float* __restrict__ hid, const float* __restrict__ W,
    const float* __restrict__ bias, float* __restrict__ hp) {
  int gw   = (blockIdx.x * 256 + threadIdx.x) >> 6;  // a
  int lane = threadIdx.x & 63;
  int a = gw;
  const float4* Wr = reinterpret_cast<const float4*>(W + (size_t)a * DD);
  float acc[BB];
#pragma unroll
  for (int b = 0; b < BB; ++b) acc[b] = 0.f;
#pragma unroll
  for (int k = 0; k < 8; ++k) {
    float4 w4 = Wr[lane + 64 * k];
#pragma unroll
    for (int b = 0; b < BB; ++b) {
      float4 h4 = reinterpret_cast<const float4*>(hid + b * DD)[lane + 64 * k];
      acc[b] += w4.x * h4.x + w4.y * h4.y + w4.z * h4.z + w4.w * h4.w;
    }
  }
  float bi = bias[a];
#pragma unroll
  for (int b = 0; b < BB; ++b) {
    float s = acc[b];
#pragma unroll
    for (int off = 32; off; off >>= 1) s += __shfl_xor(s, off, 64);
    if (lane == 0) hp[b * AA + a] = s + bi;
  }
}

// ---------------- kernel 2: vpart[ac][b][d] = sum over a-chunk of hp[b,a]*W[a,d] ----------------
// grid 128 blocks: 64 achunks (32 a each) x 2 dchunks.
__global__ __launch_bounds__(256) void vpart_kernel(
    const float* __restrict__ hp, const float* __restrict__ W,
    float* __restrict__ vpart) {
  int t  = threadIdx.x;
  int ac = blockIdx.x & 63;
  int dc = blockIdx.x >> 6;
  int d0 = dc * 1024 + 4 * t;
  float4 acc[BB];
#pragma unroll
  for (int b = 0; b < BB; ++b) acc[b] = make_float4(0.f, 0.f, 0.f, 0.f);
  int abase = ac * 32;
  for (int i = 0; i < 32; ++i) {
    int a = abase + i;
    float4 w4 = *reinterpret_cast<const float4*>(W + (size_t)a * DD + d0);
#pragma unroll
    for (int b = 0; b < BB; ++b) {
      float h = hp[b * AA + a];  // wave-uniform -> scalar load
      acc[b].x += h * w4.x; acc[b].y += h * w4.y;
      acc[b].z += h * w4.z; acc[b].w += h * w4.w;
    }
  }
#pragma unroll
  for (int b = 0; b < BB; ++b)
    *reinterpret_cast<float4*>(vpart + (size_t)(ac * BB + b) * DD + d0) = acc[b];
}

// ---------------- kernel 3: c[b] = sum_a bias[a]*hp[b,a] ----------------
__global__ __launch_bounds__(256) void c_kernel(
    const float* __restrict__ hp, const float* __restrict__ bias,
    float* __restrict__ cvec) {
  int b = blockIdx.x, t = threadIdx.x;
  float s = 0.f;
  for (int i = t; i < AA; i += 256) s += bias[i] * hp[b * AA + i];
#pragma unroll
  for (int off = 32; off; off >>= 1) s += __shfl_xor(s, off, 64);
  __shared__ float red[4];
  if ((t & 63) == 0) red[t >> 6] = s;
  __syncthreads();
  if (t == 0) cvec[b] = red[0] + red[1] + red[2] + red[3];
}

// ---------------- kernel 4: v[b,d] = sum over 64 achunks ----------------
__global__ __launch_bounds__(256) void reducev_kernel(
    const float* __restrict__ vpart, float* __restrict__ v) {
  int i = blockIdx.x * 256 + threadIdx.x;  // i = b*DD + d
  float s = 0.f;
#pragma unroll
  for (int c = 0; c < ACH; ++c) s += vpart[(size_t)c * (BB * DD) + i];
  v[i] = s;
}

// ---------------- kernel 5 (FUSED): one pass over enc ----------------
// wave = (b, chunk of 32 rows). Per row: score = enc_row·v[b] + c[b]
// (written exactly), then online-softmax weighted accumulate of the row
// (still in registers) into per-wave ctx partial.
__global__ __launch_bounds__(256) void fused_kernel(
    const float* __restrict__ enc, const float* __restrict__ v,
    const float* __restrict__ cvec, float* __restrict__ scores,
    float* __restrict__ mpart, float* __restrict__ lpart,
    float* __restrict__ ctxpart) {
  int gw   = blockIdx.x * 4 + (threadIdx.x >> 6);  // 2048 waves
  int lane = threadIdx.x & 63;
  int b  = gw >> 7;       // CH=128 chunks per b
  int ch = gw & (CH - 1);
  const float4* vp = reinterpret_cast<const float4*>(v + b * DD);
  float4 vf[8];
#pragma unroll
  for (int k = 0; k < 8; ++k) vf[k] = vp[lane + 64 * k];
  float cb = cvec[b];
  float4 acc[8];
#pragma unroll
  for (int k = 0; k < 8; ++k) acc[k] = make_float4(0.f, 0.f, 0.f, 0.f);
  float m = -1e30f, l = 0.f, myscore = 0.f;
  size_t rowbase = (size_t)(b * SS + ch * 32) * DD;
  for (int r = 0; r < 32; ++r) {
    const float4* ep = reinterpret_cast<const float4*>(enc + rowbase + (size_t)r * DD);
    float4 e[8];
#pragma unroll
    for (int k = 0; k < 8; ++k) e[k] = ep[lane + 64 * k];
    float dot = 0.f;
#pragma unroll
    for (int k = 0; k < 8; ++k)
      dot += e[k].x * vf[k].x + e[k].y * vf[k].y + e[k].z * vf[k].z + e[k].w * vf[k].w;
#pragma unroll
    for (int off = 32; off; off >>= 1) dot += __shfl_xor(dot, off, 64);
    float score = dot + cb;           // all lanes hold it
    if (lane == r) myscore = score;   // r in [0,32): lanes 0..31 keep rows
    float mnew  = fmaxf(m, score);
    float scale = __expf(m - mnew);   // 1 if max unchanged; 0 on first row
    float p     = __expf(score - mnew);
    l = l * scale + p;
#pragma unroll
    for (int k = 0; k < 8; ++k) {
      acc[k].x = acc[k].x * scale + p * e[k].x;
      acc[k].y = acc[k].y * scale + p * e[k].y;
      acc[k].z = acc[k].z * scale + p * e[k].z;
      acc[k].w = acc[k].w * scale + p * e[k].w;
    }
    m = mnew;
  }
  if (lane < 32) scores[b * SS + ch * 32 + lane] = myscore;
  if (lane == 0) { mpart[gw] = m; lpart[gw] = l; }
  float4* cp = reinterpret_cast<float4*>(ctxpart + (size_t)gw * DD);
#pragma unroll
  for (int k = 0; k < 8; ++k) cp[lane + 64 * k] = acc[k];
}

// ---------------- kernel 6: per-b softmax combine weights ----------------
// wnorm[b,c] = exp(m_c - M_b) / L_b,  L_b = sum_c l_c * exp(m_c - M_b)
__global__ __launch_bounds__(128) void mstats_kernel(
    const float* __restrict__ mpart, const float* __restrict__ lpart,
    float* __restrict__ wnorm) {
  int b = blockIdx.x, t = threadIdx.x;  // t in [0,128) = chunk
  float mt = mpart[b * CH + t];
  float lt = lpart[b * CH + t];
  float M = mt;
#pragma unroll
  for (int off = 32; off; off >>= 1) M = fmaxf(M, __shfl_xor(M, off, 64));
  __shared__ float sm[2];
  if ((t & 63) == 0) sm[t >> 6] = M;
  __syncthreads();
  M = fmaxf(sm[0], sm[1]);
  float w  = __expf(mt - M);
  float lw = lt * w;
#pragma unroll
  for (int off = 32; off; off >>= 1) lw += __shfl_xor(lw, off, 64);
  __shared__ float sl[2];
  if ((t & 63) == 0) sl[t >> 6] = lw;
  __syncthreads();
  float L = sl[0] + sl[1];
  wnorm[b * CH + t] = w / L;
}

// ---------------- kernel 7: weighted partial combine (stage 1) ----------------
// grid (b, g=0..7): part2[b,g,d] = sum_{c in g*16..} wnorm[b,c]*ctxpart[b,c,d]
__global__ __launch_bounds__(256) void combine1_kernel(
    const float* __restrict__ ctxpart, const float* __restrict__ wnorm,
    float* __restrict__ part2) {
  int b = blockIdx.x >> 3;
  int g = blockIdx.x & 7;
  int t = threadIdx.x;
  float4 a0 = make_float4(0.f, 0.f, 0.f, 0.f);
  float4 a1 = make_float4(0.f, 0.f, 0.f, 0.f);
  for (int i = 0; i < 16; ++i) {
    int c = g * 16 + i;
    float w = wnorm[b * CH + c];  // wave-uniform
    const float4* cp = reinterpret_cast<const float4*>(ctxpart + (size_t)(b * CH + c) * DD);
    float4 e0 = cp[t];
    float4 e1 = cp[t + 256];
    a0.x += w * e0.x; a0.y += w * e0.y; a0.z += w * e0.z; a0.w += w * e0.w;
    a1.x += w * e1.x; a1.y += w * e1.y; a1.z += w * e1.z; a1.w += w * e1.w;
  }
  float4* o = reinterpret_cast<float4*>(part2 + (size_t)(b * 8 + g) * DD);
  o[t] = a0;
  o[t + 256] = a1;
}

// ---------------- kernel 8: final ctx reduce (stage 2) ----------------
__global__ __launch_bounds__(256) void combine2_kernel(
    const float* __restrict__ part2, float* __restrict__ ctx) {
  int i = blockIdx.x * 256 + threadIdx.x;  // [0, BB*DD)
  int b = i >> 11;
  int d = i & 2047;
  float s = 0.f;
#pragma unroll
  for (int g = 0; g < 8; ++g) s += part2[(size_t)(b * 8 + g) * DD + d];
  ctx[i] = s;
}

extern "C" void kernel_launch(void* const* d_in, const int* in_sizes, int n_in,
                              void* d_out, int out_size, void* d_ws, size_t ws_size,
                              hipStream_t stream) {
  const float* enc  = (const float*)d_in[0];  // [B,S,D]
  const float* hid  = (const float*)d_in[1];  // [B,D]
  const float* W    = (const float*)d_in[2];  // [A,D]
  const float* bias = (const float*)d_in[3];  // [A]

  float* out_scores = (float*)d_out;            // [B,S]
  float* out_ctx    = (float*)d_out + BB * SS;  // [B,D]

  float* ws    = (float*)d_ws;
  float* hp    = ws;                        // B*A            = 32768
  float* vpart = hp + BB * AA;              // ACH*B*D        = 2097152
  float* v     = vpart + ACH * BB * DD;     // B*D            = 32768
  float* cvec  = v + BB * DD;               // B              = 16
  float* mpart = cvec + BB;                 // B*CH           = 2048
  float* lpart = mpart + BB * CH;           // B*CH           = 2048
  float* wnorm = lpart + BB * CH;           // B*CH           = 2048
  float* ctxp  = wnorm + BB * CH;           // B*CH*D         = 4194304
  float* part2 = ctxp + (size_t)BB * CH * DD;  // B*8*D       = 262144
  // total ~26.5 MB

  hipLaunchKernelGGL(hp_kernel,      dim3(512), dim3(256), 0, stream, hid, W, bias, hp);
  hipLaunchKernelGGL(vpart_kernel,   dim3(128), dim3(256), 0, stream, hp, W, vpart);
  hipLaunchKernelGGL(c_kernel,       dim3(16),  dim3(256), 0, stream, hp, bias, cvec);
  hipLaunchKernelGGL(reducev_kernel, dim3(128), dim3(256), 0, stream, vpart, v);
  hipLaunchKernelGGL(fused_kernel,   dim3(512), dim3(256), 0, stream,
                     enc, v, cvec, out_scores, mpart, lpart, ctxp);
  hipLaunchKernelGGL(mstats_kernel,  dim3(16),  dim3(128), 0, stream, mpart, lpart, wnorm);
  hipLaunchKernelGGL(combine1_kernel, dim3(128), dim3(256), 0, stream, ctxp, wnorm, part2);
  hipLaunchKernelGGL(combine2_kernel, dim3(128), dim3(256), 0, stream, part2, out_ctx);
}